// Round 9
// baseline (828.842 us; speedup 1.0000x reference)
//
#include <hip/hip_runtime.h>
#include <float.h>

#define WAY   5
#define SHOT  5
#define DIM   640
#define KTOP  16
#define EPSN  1e-8f

// Kernel B geometry: 8 rows per wave-iter (2 sets of 4 rows x 16 lanes)
#define B_BLOCKS  1024
#define B_THREADS 256
#define WPB       (B_THREADS / 64)
#define B_WAVES   (B_BLOCKS * WPB)          // 4096
#define RPI       8
#define ROWSTRIDE (B_WAVES * RPI)           // 32768 rows per sweep

// ws layout: simAll [WAY][M] at offset 0 (only ws user)

typedef float floatx4 __attribute__((ext_vector_type(4)));

__device__ __forceinline__ float blockReduce256(float v, float* sred) {
#pragma unroll
  for (int off = 32; off >= 1; off >>= 1) v += __shfl_xor(v, off, 64);
  __syncthreads();
  if ((threadIdx.x & 63) == 0) sred[threadIdx.x >> 6] = v;
  __syncthreads();
  return sred[0] + sred[1] + sred[2] + sred[3];
}

// ---- DPP: reduce within 16-lane groups, pure VALU ----
template <int CTRL>
__device__ __forceinline__ float dppMov(float x) {
  int r = __builtin_amdgcn_update_dpp(0, __builtin_bit_cast(int, x), CTRL, 0xF, 0xF, true);
  return __builtin_bit_cast(float, r);
}
__device__ __forceinline__ float rowReduce16(float v) {
  v += dppMov<0x128>(v);  // row_ror:8
  v += dppMov<0x124>(v);  // row_ror:4
  v += dppMov<0x122>(v);  // row_ror:2
  v += dppMov<0x121>(v);  // row_ror:1
  return v;
}

// ---- build 5 normalized protos into LDS sP[WAY*DIM] (all 256 threads) ----
__device__ __forceinline__ void buildProtosLDS(
    const float* __restrict__ support, float* sP, float* sred) {
  const int tid = threadIdx.x;
  // phase 1: means
  for (int idx = tid; idx < WAY * DIM; idx += B_THREADS) {
    const int w = idx / DIM, t = idx - w * DIM;
    float v = 0.f;
#pragma unroll
    for (int s = 0; s < SHOT; ++s) v += support[(s * WAY + w) * DIM + t];
    sP[w * DIM + t] = v * (1.0f / SHOT);
  }
  __syncthreads();
  // phase 2: per-way l2 normalize
  for (int w = 0; w < WAY; ++w) {
    float n2 = 0.f;
#pragma unroll
    for (int c = 0; c < 3; ++c) {
      const int t = tid + 256 * c;
      if (t < DIM) { const float m = sP[w * DIM + t]; n2 = fmaf(m, m, n2); }
    }
    n2 = blockReduce256(n2, sred);
    const float inv = 1.0f / fmaxf(sqrtf(n2), EPSN);
#pragma unroll
    for (int c = 0; c < 3; ++c) {
      const int t = tid + 256 * c;
      if (t < DIM) sP[w * DIM + t] *= inv;
    }
  }
  __syncthreads();
}

// ---- Kernel B1': fused proto build + stream (NT loads) -> simAll ----
__global__ __launch_bounds__(B_THREADS) void simB1f_kernel(
    const float* __restrict__ support, const float* __restrict__ memory,
    float* __restrict__ simAll, int M) {
  __shared__ float sP[WAY * DIM];   // 12.8 KB
  __shared__ float sred[4];
  buildProtosLDS(support, sP, sred);

  const int lane = threadIdx.x & 63;
  const int sub  = lane & 15;
  const int grp  = lane >> 4;
  const int waveId = blockIdx.x * WPB + (threadIdx.x >> 6);
  const int colOff = sub * 4;
  const float* sPc = sP + colOff;

  for (int base = waveId * RPI; base < M; base += ROWSTRIDE) {
    const int rA = base + grp;
    const int rB = base + 4 + grp;
    const bool okA = (rA < M);
    const bool okB = (rB < M);
    const size_t offA = (size_t)(okA ? rA : (M - 1)) * DIM + colOff;
    const size_t offB = (size_t)(okB ? rB : (M - 1)) * DIM + colOff;

    float nA = 0.f, a0 = 0.f, a1 = 0.f, a2 = 0.f, a3 = 0.f, a4 = 0.f;
    float nB = 0.f, b0 = 0.f, b1 = 0.f, b2 = 0.f, b3 = 0.f, b4 = 0.f;
#pragma unroll
    for (int it = 0; it < 10; ++it) {
      const floatx4 xa = __builtin_nontemporal_load((const floatx4*)&memory[offA + it * 64]);
      const floatx4 xb = __builtin_nontemporal_load((const floatx4*)&memory[offB + it * 64]);
      const float4 p0 = *(const float4*)&sPc[0 * DIM + it * 64];
      const float4 p1 = *(const float4*)&sPc[1 * DIM + it * 64];
      const float4 p2 = *(const float4*)&sPc[2 * DIM + it * 64];
      const float4 p3 = *(const float4*)&sPc[3 * DIM + it * 64];
      const float4 p4 = *(const float4*)&sPc[4 * DIM + it * 64];
      nA = fmaf(xa.x, xa.x, fmaf(xa.y, xa.y, fmaf(xa.z, xa.z, fmaf(xa.w, xa.w, nA))));
      a0 = fmaf(xa.x, p0.x, fmaf(xa.y, p0.y, fmaf(xa.z, p0.z, fmaf(xa.w, p0.w, a0))));
      a1 = fmaf(xa.x, p1.x, fmaf(xa.y, p1.y, fmaf(xa.z, p1.z, fmaf(xa.w, p1.w, a1))));
      a2 = fmaf(xa.x, p2.x, fmaf(xa.y, p2.y, fmaf(xa.z, p2.z, fmaf(xa.w, p2.w, a2))));
      a3 = fmaf(xa.x, p3.x, fmaf(xa.y, p3.y, fmaf(xa.z, p3.z, fmaf(xa.w, p3.w, a3))));
      a4 = fmaf(xa.x, p4.x, fmaf(xa.y, p4.y, fmaf(xa.z, p4.z, fmaf(xa.w, p4.w, a4))));
      nB = fmaf(xb.x, xb.x, fmaf(xb.y, xb.y, fmaf(xb.z, xb.z, fmaf(xb.w, xb.w, nB))));
      b0 = fmaf(xb.x, p0.x, fmaf(xb.y, p0.y, fmaf(xb.z, p0.z, fmaf(xb.w, p0.w, b0))));
      b1 = fmaf(xb.x, p1.x, fmaf(xb.y, p1.y, fmaf(xb.z, p1.z, fmaf(xb.w, p1.w, b1))));
      b2 = fmaf(xb.x, p2.x, fmaf(xb.y, p2.y, fmaf(xb.z, p2.z, fmaf(xb.w, p2.w, b2))));
      b3 = fmaf(xb.x, p3.x, fmaf(xb.y, p3.y, fmaf(xb.z, p3.z, fmaf(xb.w, p3.w, b3))));
      b4 = fmaf(xb.x, p4.x, fmaf(xb.y, p4.y, fmaf(xb.z, p4.z, fmaf(xb.w, p4.w, b4))));
    }

    const float rA0 = rowReduce16(a0), rA1 = rowReduce16(a1), rA2 = rowReduce16(a2);
    const float rA3 = rowReduce16(a3), rA4 = rowReduce16(a4), rAn = rowReduce16(nA);
    const float rB0 = rowReduce16(b0), rB1 = rowReduce16(b1), rB2 = rowReduce16(b2);
    const float rB3 = rowReduce16(b3), rB4 = rowReduce16(b4), rBn = rowReduce16(nB);

    const float sA = 0.2f / fmaxf(sqrtf(rAn), EPSN);
    const float sB = 0.2f / fmaxf(sqrtf(rBn), EPSN);
    float vA = rA0, vB = rB0;
    vA = (sub == 1) ? rA1 : vA;  vB = (sub == 1) ? rB1 : vB;
    vA = (sub == 2) ? rA2 : vA;  vB = (sub == 2) ? rB2 : vB;
    vA = (sub == 3) ? rA3 : vA;  vB = (sub == 3) ? rB3 : vB;
    vA = (sub == 4) ? rA4 : vA;  vB = (sub == 4) ? rB4 : vB;
    if (okA && sub < WAY) simAll[(size_t)sub * M + rA] = vA * sA;
    if (okB && sub < WAY) simAll[(size_t)sub * M + rB] = vB * sB;
  }
}

// ---- Kernel CDE': per-way proto + support sims + top-16 + proto + logits ----
__global__ __launch_bounds__(256) void cdeF_kernel(
    const float* __restrict__ support, const float* __restrict__ query,
    const float* __restrict__ memory, const float* __restrict__ simAll,
    float* __restrict__ out, int M) {
  const int w = blockIdx.x;
  const int tid = threadIdx.x;
  __shared__ float prot[DIM];        // normalized basic proto, later weighted proto
  __shared__ float simsup[SHOT];
  __shared__ float sred[4];

  // basic proto for way w (exact protoA arithmetic)
  float m[3];
  float n2 = 0.f;
#pragma unroll
  for (int c = 0; c < 3; ++c) {
    const int t = tid + 256 * c;
    float v = 0.f;
    if (t < DIM) {
#pragma unroll
      for (int s = 0; s < SHOT; ++s) v += support[(s * WAY + w) * DIM + t];
      v *= (1.0f / SHOT);
    }
    m[c] = v;
    n2 += v * v;
  }
  n2 = blockReduce256(n2, sred);
  const float inv0 = 1.0f / fmaxf(sqrtf(n2), EPSN);
#pragma unroll
  for (int c = 0; c < 3; ++c) {
    const int t = tid + 256 * c;
    if (t < DIM) prot[t] = m[c] * inv0;
  }

  // support sims
  for (int s = 0; s < SHOT; ++s) {
    float dot = 0.f, sn2 = 0.f;
#pragma unroll
    for (int c = 0; c < 3; ++c) {
      const int t = tid + 256 * c;
      if (t < DIM) {
        const float sv = support[(s * WAY + w) * DIM + t];
        dot += sv * (m[c] * inv0);
        sn2 += sv * sv;
      }
    }
    dot = blockReduce256(dot, sred);
    sn2 = blockReduce256(sn2, sred);
    if (tid == 0) simsup[s] = dot / fmaxf(sqrtf(sn2), EPSN);
  }
  __syncthreads();

  // per-thread register top-16 over simAll[w][*]
  float lv[KTOP];
  int   li[KTOP];
#pragma unroll
  for (int k = 0; k < KTOP; ++k) { lv[k] = -FLT_MAX; li[k] = 0; }
  if (tid < SHOT) { lv[0] = simsup[tid]; li[0] = tid; }

  const float* sv = simAll + (size_t)w * M;
  for (int i = tid; i < M; i += 256) {
    const float v = sv[i];
    if (v > lv[KTOP - 1]) {
      const int id = SHOT + i;
#pragma unroll
      for (int j = KTOP - 1; j >= 1; --j) {
        const float up = lv[j - 1];
        const int   ui = li[j - 1];
        const bool shift = (up < v);
        const float cur = lv[j];
        const int  curi = li[j];
        lv[j] = shift ? up : (cur < v ? v : cur);
        li[j] = shift ? ui : (cur < v ? id : curi);
      }
      if (lv[0] < v) { li[0] = id; lv[0] = v; }
    }
  }

  __shared__ float sLV[256][KTOP];
  __shared__ int   sLI[256][KTOP];
  __shared__ float outV[KTOP];
  __shared__ int   outI[KTOP];
  __shared__ float sWv[4];
  __shared__ int   sWi[4];
#pragma unroll
  for (int k = 0; k < KTOP; ++k) { sLV[tid][k] = lv[k]; sLI[tid][k] = li[k]; }
  __syncthreads();

  int cursor = 0;
  for (int r = 0; r < KTOP; ++r) {
    float v = (cursor < KTOP) ? sLV[tid][cursor] : -FLT_MAX;
    int   t = tid;
#pragma unroll
    for (int off = 32; off >= 1; off >>= 1) {
      const float ov = __shfl_xor(v, off, 64);
      const int   ot = __shfl_xor(t, off, 64);
      if (ov > v) { v = ov; t = ot; }
    }
    __syncthreads();
    if ((tid & 63) == 0) { sWv[tid >> 6] = v; sWi[tid >> 6] = t; }
    __syncthreads();
    float bv = sWv[0]; int bt = sWi[0];
#pragma unroll
    for (int q = 1; q < 4; ++q)
      if (sWv[q] > bv) { bv = sWv[q]; bt = sWi[q]; }
    if (tid == bt) {
      outV[r] = sLV[tid][cursor];
      outI[r] = sLI[tid][cursor];
      ++cursor;
    }
    __syncthreads();
  }

  float sumW = 0.f;
#pragma unroll
  for (int k = 0; k < KTOP; ++k) sumW += outV[k];

  // weighted prototype + l2norm -> prot[] (reuse)
  float pw[3];
  float pn2 = 0.f;
#pragma unroll
  for (int c = 0; c < 3; ++c) {
    const int t = tid + 256 * c;
    float acc = 0.f;
    if (t < DIM) {
#pragma unroll
      for (int k = 0; k < KTOP; ++k) {
        const int gi = outI[k];
        const float* emb = (gi < SHOT)
            ? (support + (size_t)(gi * WAY + w) * DIM)
            : (memory + (size_t)(gi - SHOT) * DIM);
        acc += outV[k] * emb[t];
      }
      acc /= sumW;
    }
    pw[c] = acc;
    pn2 += acc * acc;
  }
  pn2 = blockReduce256(pn2, sred);
  const float inv1 = 1.0f / fmaxf(sqrtf(pn2), EPSN);
  __syncthreads();   // prot[] no longer needed as basic proto
#pragma unroll
  for (int c = 0; c < 3; ++c) {
    const int t = tid + 256 * c;
    if (t < DIM) prot[t] = pw[c] * inv1;
  }
  __syncthreads();

  // logits: 4 waves, wave wv handles queries wv, wv+4, ...
  const int lane = tid & 63;
  const int wv = tid >> 6;
  for (int q = wv; q < 75; q += 4) {
    const float* qr = query + (size_t)q * DIM;
    float acc = 0.f;
#pragma unroll
    for (int k = 0; k < 5; ++k) {
      const float2 a = *(const float2*)&qr[2 * (lane + 64 * k)];
      const float2 b = *(const float2*)&prot[2 * (lane + 64 * k)];
      acc += a.x * b.x + a.y * b.y;
    }
#pragma unroll
    for (int off = 32; off >= 1; off >>= 1) acc += __shfl_xor(acc, off, 64);
    if (lane == 0) out[q * WAY + w] = acc * (1.0f / 64.0f);
  }
}

extern "C" void kernel_launch(void* const* d_in, const int* in_sizes, int n_in,
                              void* d_out, int out_size, void* d_ws, size_t ws_size,
                              hipStream_t stream) {
  const float* support = (const float*)d_in[0];
  const float* query   = (const float*)d_in[1];
  const float* memory  = (const float*)d_in[2];
  float* out = (float*)d_out;
  float* simAll = (float*)d_ws;
  const int M = in_sizes[2] / DIM;

  hipLaunchKernelGGL(simB1f_kernel, dim3(B_BLOCKS), dim3(B_THREADS), 0, stream,
                     support, memory, simAll, M);
  hipLaunchKernelGGL(cdeF_kernel, dim3(WAY), dim3(256), 0, stream,
                     support, query, memory, simAll, out, M);
}

// Round 10
// 183.270 us; speedup vs baseline: 4.5225x; 4.5225x over previous
//
#include <hip/hip_runtime.h>
#include <float.h>

#define WAY   5
#define SHOT  5
#define DIM   640
#define KTOP  16
#define EPSN  1e-8f

// Kernel B geometry: 8 rows per wave-iter (2 sets of 4 rows x 16 lanes)
#define B_BLOCKS  1024
#define B_THREADS 256
#define WPB       (B_THREADS / 64)
#define B_WAVES   (B_BLOCKS * WPB)          // 4096
#define RPI       8
#define ROWSTRIDE (B_WAVES * RPI)           // 32768 rows per sweep

// Top-k reduction geometry
#define SEGS   32
#define CANDS  (SEGS * KTOP)   // 512 candidates per way

typedef float floatx4 __attribute__((ext_vector_type(4)));

__device__ __forceinline__ float blockReduce256(float v, float* sred) {
#pragma unroll
  for (int off = 32; off >= 1; off >>= 1) v += __shfl_xor(v, off, 64);
  __syncthreads();
  if ((threadIdx.x & 63) == 0) sred[threadIdx.x >> 6] = v;
  __syncthreads();
  return sred[0] + sred[1] + sred[2] + sred[3];
}

// ---- DPP: reduce within 16-lane groups, pure VALU ----
template <int CTRL>
__device__ __forceinline__ float dppMov(float x) {
  int r = __builtin_amdgcn_update_dpp(0, __builtin_bit_cast(int, x), CTRL, 0xF, 0xF, true);
  return __builtin_bit_cast(float, r);
}
__device__ __forceinline__ float rowReduce16(float v) {
  v += dppMov<0x128>(v);  // row_ror:8
  v += dppMov<0x124>(v);  // row_ror:4
  v += dppMov<0x122>(v);  // row_ror:2
  v += dppMov<0x121>(v);  // row_ror:1
  return v;
}

// ---- build 5 normalized protos into LDS sP[WAY*DIM] (all 256 threads) ----
__device__ __forceinline__ void buildProtosLDS(
    const float* __restrict__ support, float* sP, float* sred) {
  const int tid = threadIdx.x;
  for (int idx = tid; idx < WAY * DIM; idx += B_THREADS) {
    const int w = idx / DIM, t = idx - w * DIM;
    float v = 0.f;
#pragma unroll
    for (int s = 0; s < SHOT; ++s) v += support[(s * WAY + w) * DIM + t];
    sP[w * DIM + t] = v * (1.0f / SHOT);
  }
  __syncthreads();
  for (int w = 0; w < WAY; ++w) {
    float n2 = 0.f;
#pragma unroll
    for (int c = 0; c < 3; ++c) {
      const int t = tid + 256 * c;
      if (t < DIM) { const float m = sP[w * DIM + t]; n2 = fmaf(m, m, n2); }
    }
    n2 = blockReduce256(n2, sred);
    const float inv = 1.0f / fmaxf(sqrtf(n2), EPSN);
#pragma unroll
    for (int c = 0; c < 3; ++c) {
      const int t = tid + 256 * c;
      if (t < DIM) sP[w * DIM + t] *= inv;
    }
  }
  __syncthreads();
}

// ---- Kernel B1': fused proto build + NT stream -> simAll [WAY][M] ----
__global__ __launch_bounds__(B_THREADS) void simB1f_kernel(
    const float* __restrict__ support, const float* __restrict__ memory,
    float* __restrict__ simAll, int M) {
  __shared__ float sP[WAY * DIM];   // 12.8 KB
  __shared__ float sred[4];
  buildProtosLDS(support, sP, sred);

  const int lane = threadIdx.x & 63;
  const int sub  = lane & 15;
  const int grp  = lane >> 4;
  const int waveId = blockIdx.x * WPB + (threadIdx.x >> 6);
  const int colOff = sub * 4;
  const float* sPc = sP + colOff;

  for (int base = waveId * RPI; base < M; base += ROWSTRIDE) {
    const int rA = base + grp;
    const int rB = base + 4 + grp;
    const bool okA = (rA < M);
    const bool okB = (rB < M);
    const size_t offA = (size_t)(okA ? rA : (M - 1)) * DIM + colOff;
    const size_t offB = (size_t)(okB ? rB : (M - 1)) * DIM + colOff;

    float nA = 0.f, a0 = 0.f, a1 = 0.f, a2 = 0.f, a3 = 0.f, a4 = 0.f;
    float nB = 0.f, b0 = 0.f, b1 = 0.f, b2 = 0.f, b3 = 0.f, b4 = 0.f;
#pragma unroll
    for (int it = 0; it < 10; ++it) {
      const floatx4 xa = __builtin_nontemporal_load((const floatx4*)&memory[offA + it * 64]);
      const floatx4 xb = __builtin_nontemporal_load((const floatx4*)&memory[offB + it * 64]);
      const float4 p0 = *(const float4*)&sPc[0 * DIM + it * 64];
      const float4 p1 = *(const float4*)&sPc[1 * DIM + it * 64];
      const float4 p2 = *(const float4*)&sPc[2 * DIM + it * 64];
      const float4 p3 = *(const float4*)&sPc[3 * DIM + it * 64];
      const float4 p4 = *(const float4*)&sPc[4 * DIM + it * 64];
      nA = fmaf(xa.x, xa.x, fmaf(xa.y, xa.y, fmaf(xa.z, xa.z, fmaf(xa.w, xa.w, nA))));
      a0 = fmaf(xa.x, p0.x, fmaf(xa.y, p0.y, fmaf(xa.z, p0.z, fmaf(xa.w, p0.w, a0))));
      a1 = fmaf(xa.x, p1.x, fmaf(xa.y, p1.y, fmaf(xa.z, p1.z, fmaf(xa.w, p1.w, a1))));
      a2 = fmaf(xa.x, p2.x, fmaf(xa.y, p2.y, fmaf(xa.z, p2.z, fmaf(xa.w, p2.w, a2))));
      a3 = fmaf(xa.x, p3.x, fmaf(xa.y, p3.y, fmaf(xa.z, p3.z, fmaf(xa.w, p3.w, a3))));
      a4 = fmaf(xa.x, p4.x, fmaf(xa.y, p4.y, fmaf(xa.z, p4.z, fmaf(xa.w, p4.w, a4))));
      nB = fmaf(xb.x, xb.x, fmaf(xb.y, xb.y, fmaf(xb.z, xb.z, fmaf(xb.w, xb.w, nB))));
      b0 = fmaf(xb.x, p0.x, fmaf(xb.y, p0.y, fmaf(xb.z, p0.z, fmaf(xb.w, p0.w, b0))));
      b1 = fmaf(xb.x, p1.x, fmaf(xb.y, p1.y, fmaf(xb.z, p1.z, fmaf(xb.w, p1.w, b1))));
      b2 = fmaf(xb.x, p2.x, fmaf(xb.y, p2.y, fmaf(xb.z, p2.z, fmaf(xb.w, p2.w, b2))));
      b3 = fmaf(xb.x, p3.x, fmaf(xb.y, p3.y, fmaf(xb.z, p3.z, fmaf(xb.w, p3.w, b3))));
      b4 = fmaf(xb.x, p4.x, fmaf(xb.y, p4.y, fmaf(xb.z, p4.z, fmaf(xb.w, p4.w, b4))));
    }

    const float rA0 = rowReduce16(a0), rA1 = rowReduce16(a1), rA2 = rowReduce16(a2);
    const float rA3 = rowReduce16(a3), rA4 = rowReduce16(a4), rAn = rowReduce16(nA);
    const float rB0 = rowReduce16(b0), rB1 = rowReduce16(b1), rB2 = rowReduce16(b2);
    const float rB3 = rowReduce16(b3), rB4 = rowReduce16(b4), rBn = rowReduce16(nB);

    const float sA = 0.2f / fmaxf(sqrtf(rAn), EPSN);
    const float sB = 0.2f / fmaxf(sqrtf(rBn), EPSN);
    float vA = rA0, vB = rB0;
    vA = (sub == 1) ? rA1 : vA;  vB = (sub == 1) ? rB1 : vB;
    vA = (sub == 2) ? rA2 : vA;  vB = (sub == 2) ? rB2 : vB;
    vA = (sub == 3) ? rA3 : vA;  vB = (sub == 3) ? rB3 : vB;
    vA = (sub == 4) ? rA4 : vA;  vB = (sub == 4) ? rB4 : vB;
    if (okA && sub < WAY) simAll[(size_t)sub * M + rA] = vA * sA;
    if (okB && sub < WAY) simAll[(size_t)sub * M + rB] = vB * sB;
  }
}

// -------- Kernel C1: per-(way,segment) partial top-16 over simAll ---------
__global__ __launch_bounds__(256) void topkC1_kernel(
    const float* __restrict__ simAll, float* __restrict__ candV,
    int* __restrict__ candI, int M) {
  const int w   = blockIdx.x / SEGS;
  const int seg = blockIdx.x % SEGS;
  const int tid = threadIdx.x;
  const int len = (M + SEGS - 1) / SEGS;
  const int i0 = seg * len;
  const int i1 = min(i0 + len, M);

  float lv[KTOP];
  int   li[KTOP];
#pragma unroll
  for (int k = 0; k < KTOP; ++k) { lv[k] = -FLT_MAX; li[k] = 0; }

  const float* sv = simAll + (size_t)w * M;
  for (int i = i0 + tid; i < i1; i += 256) {
    const float v = sv[i];
    if (v > lv[KTOP - 1]) {
      const int id = SHOT + i;
#pragma unroll
      for (int j = KTOP - 1; j >= 1; --j) {
        const float up = lv[j - 1];
        const int   ui = li[j - 1];
        const bool shift = (up < v);
        const float cur = lv[j];
        const int  curi = li[j];
        lv[j] = shift ? up : (cur < v ? v : cur);
        li[j] = shift ? ui : (cur < v ? id : curi);
      }
      if (lv[0] < v) { li[0] = id; lv[0] = v; }
    }
  }

  __shared__ float sLV[256][KTOP];
  __shared__ int   sLI[256][KTOP];
  __shared__ float sWv[4];
  __shared__ int   sWi[4];
#pragma unroll
  for (int k = 0; k < KTOP; ++k) { sLV[tid][k] = lv[k]; sLI[tid][k] = li[k]; }
  __syncthreads();

  int cursor = 0;
  for (int r = 0; r < KTOP; ++r) {
    float v = (cursor < KTOP) ? sLV[tid][cursor] : -FLT_MAX;
    int   t = tid;
#pragma unroll
    for (int off = 32; off >= 1; off >>= 1) {
      const float ov = __shfl_xor(v, off, 64);
      const int   ot = __shfl_xor(t, off, 64);
      if (ov > v) { v = ov; t = ot; }
    }
    __syncthreads();
    if ((tid & 63) == 0) { sWv[tid >> 6] = v; sWi[tid >> 6] = t; }
    __syncthreads();
    float bv = sWv[0]; int bt = sWi[0];
#pragma unroll
    for (int q = 1; q < 4; ++q)
      if (sWv[q] > bv) { bv = sWv[q]; bt = sWi[q]; }
    if (tid == bt) {
      candV[(size_t)(w * SEGS + seg) * KTOP + r] = sLV[tid][cursor];
      candI[(size_t)(w * SEGS + seg) * KTOP + r] = sLI[tid][cursor];
      ++cursor;
    }
    __syncthreads();
  }
}

// -- Kernel C2': per-way: basic proto + support sims + merge + weighted proto --
__global__ __launch_bounds__(256) void topkProtoC2_kernel(
    const float* __restrict__ support, const float* __restrict__ memory,
    const float* __restrict__ candV, const int* __restrict__ candI,
    float* __restrict__ protoW, int M) {
  const int w = blockIdx.x;
  const int tid = threadIdx.x;
  __shared__ float simsup[SHOT];
  __shared__ float sred[4];

  // basic proto (registers) + support sims (exact protoA arithmetic)
  float m[3];
  float n2 = 0.f;
#pragma unroll
  for (int c = 0; c < 3; ++c) {
    const int t = tid + 256 * c;
    float v = 0.f;
    if (t < DIM) {
#pragma unroll
      for (int s = 0; s < SHOT; ++s) v += support[(s * WAY + w) * DIM + t];
      v *= (1.0f / SHOT);
    }
    m[c] = v;
    n2 += v * v;
  }
  n2 = blockReduce256(n2, sred);
  const float inv0 = 1.0f / fmaxf(sqrtf(n2), EPSN);

  for (int s = 0; s < SHOT; ++s) {
    float dot = 0.f, sn2 = 0.f;
#pragma unroll
    for (int c = 0; c < 3; ++c) {
      const int t = tid + 256 * c;
      if (t < DIM) {
        const float sv = support[(s * WAY + w) * DIM + t];
        dot += sv * (m[c] * inv0);
        sn2 += sv * sv;
      }
    }
    dot = blockReduce256(dot, sred);
    sn2 = blockReduce256(sn2, sred);
    if (tid == 0) simsup[s] = dot / fmaxf(sqrtf(sn2), EPSN);
  }
  __syncthreads();

  // per-thread top-16 over 512 candidates, seeded with support sims
  float lv[KTOP];
  int   li[KTOP];
#pragma unroll
  for (int k = 0; k < KTOP; ++k) { lv[k] = -FLT_MAX; li[k] = 0; }
  if (tid < SHOT) { lv[0] = simsup[tid]; li[0] = tid; }

  const float* cv = candV + (size_t)w * CANDS;
  const int*   ci = candI + (size_t)w * CANDS;
  for (int i = tid; i < CANDS; i += 256) {
    const float v = cv[i];
    if (v > lv[KTOP - 1]) {
      const int id = ci[i];
#pragma unroll
      for (int j = KTOP - 1; j >= 1; --j) {
        const float up = lv[j - 1];
        const int   ui = li[j - 1];
        const bool shift = (up < v);
        const float cur = lv[j];
        const int  curi = li[j];
        lv[j] = shift ? up : (cur < v ? v : cur);
        li[j] = shift ? ui : (cur < v ? id : curi);
      }
      if (lv[0] < v) { li[0] = id; lv[0] = v; }
    }
  }

  __shared__ float sLV[256][KTOP];
  __shared__ int   sLI[256][KTOP];
  __shared__ float outV[KTOP];
  __shared__ int   outI[KTOP];
  __shared__ float sWv[4];
  __shared__ int   sWi[4];
#pragma unroll
  for (int k = 0; k < KTOP; ++k) { sLV[tid][k] = lv[k]; sLI[tid][k] = li[k]; }
  __syncthreads();

  int cursor = 0;
  for (int r = 0; r < KTOP; ++r) {
    float v = (cursor < KTOP) ? sLV[tid][cursor] : -FLT_MAX;
    int   t = tid;
#pragma unroll
    for (int off = 32; off >= 1; off >>= 1) {
      const float ov = __shfl_xor(v, off, 64);
      const int   ot = __shfl_xor(t, off, 64);
      if (ov > v) { v = ov; t = ot; }
    }
    __syncthreads();
    if ((tid & 63) == 0) { sWv[tid >> 6] = v; sWi[tid >> 6] = t; }
    __syncthreads();
    float bv = sWv[0]; int bt = sWi[0];
#pragma unroll
    for (int q = 1; q < 4; ++q)
      if (sWv[q] > bv) { bv = sWv[q]; bt = sWi[q]; }
    if (tid == bt) {
      outV[r] = sLV[tid][cursor];
      outI[r] = sLI[tid][cursor];
      ++cursor;
    }
    __syncthreads();
  }

  float sumW = 0.f;
#pragma unroll
  for (int k = 0; k < KTOP; ++k) sumW += outV[k];

  float pw[3];
  float pn2 = 0.f;
#pragma unroll
  for (int c = 0; c < 3; ++c) {
    const int t = tid + 256 * c;
    float acc = 0.f;
    if (t < DIM) {
#pragma unroll
      for (int k = 0; k < KTOP; ++k) {
        const int gi = outI[k];
        const float* emb = (gi < SHOT)
            ? (support + (size_t)(gi * WAY + w) * DIM)
            : (memory + (size_t)(gi - SHOT) * DIM);
        acc += outV[k] * emb[t];
      }
      acc /= sumW;
    }
    pw[c] = acc;
    pn2 += acc * acc;
  }
  pn2 = blockReduce256(pn2, sred);
  const float inv1 = 1.0f / fmaxf(sqrtf(pn2), EPSN);
#pragma unroll
  for (int c = 0; c < 3; ++c) {
    const int t = tid + 256 * c;
    if (t < DIM) protoW[w * DIM + t] = pw[c] * inv1;
  }
}

// ---------------- Kernel D: logits = q . proto_n / T ----------------------
__global__ __launch_bounds__(64) void logitsD_kernel(
    const float* __restrict__ query, const float* __restrict__ protoW,
    float* __restrict__ out) {
  const int q = blockIdx.x;
  const int p = blockIdx.y;
  const int lane = threadIdx.x;
  const float* qr = query + (size_t)q * DIM;
  const float* pn = protoW + p * DIM;
  float acc = 0.f;
#pragma unroll
  for (int k = 0; k < 5; ++k) {
    const float2 a = *(const float2*)&qr[2 * (lane + 64 * k)];
    const float2 b = *(const float2*)&pn[2 * (lane + 64 * k)];
    acc += a.x * b.x + a.y * b.y;
  }
#pragma unroll
  for (int off = 32; off >= 1; off >>= 1) acc += __shfl_xor(acc, off, 64);
  if (lane == 0) out[q * WAY + p] = acc * (1.0f / 64.0f);
}

extern "C" void kernel_launch(void* const* d_in, const int* in_sizes, int n_in,
                              void* d_out, int out_size, void* d_ws, size_t ws_size,
                              hipStream_t stream) {
  const float* support = (const float*)d_in[0];
  const float* query   = (const float*)d_in[1];
  const float* memory  = (const float*)d_in[2];
  float* out = (float*)d_out;
  float* ws  = (float*)d_ws;
  const int M = in_sizes[2] / DIM;

  float* simAll = ws;                                   // [WAY][M]
  float* candV  = ws + (size_t)WAY * M;                 // [WAY][CANDS]
  int*   candI  = (int*)(candV + WAY * CANDS);          // [WAY][CANDS]
  float* protoW = (float*)(candI + WAY * CANDS);        // [WAY][DIM]

  hipLaunchKernelGGL(simB1f_kernel, dim3(B_BLOCKS), dim3(B_THREADS), 0, stream,
                     support, memory, simAll, M);
  hipLaunchKernelGGL(topkC1_kernel, dim3(WAY * SEGS), dim3(256), 0, stream,
                     simAll, candV, candI, M);
  hipLaunchKernelGGL(topkProtoC2_kernel, dim3(WAY), dim3(256), 0, stream,
                     support, memory, candV, candI, protoW, M);
  hipLaunchKernelGGL(logitsD_kernel, dim3(75, WAY), dim3(64), 0, stream,
                     query, protoW, out);
}